// Round 9
// baseline (198.878 us; speedup 1.0000x reference)
//
#include <hip/hip_runtime.h>
#include <hip/hip_bf16.h>

// CIN (xDeepFM) fused 3-layer kernel for MI355X — R21: R20 (gs-split W
// dedup + 4-deep step2) + amdgpu_waves_per_eu(2,2) to stop the allocator
// from spilling for unreachable occupancy.
// R20 post-mortem: VGPR_Count=128 WITH (512,1) and 70MB scratch FETCH ->
// hipcc's allocator targets 4 waves/EU ignoring that LDS (112KB) already
// caps us at 1 WG = 2 waves/EU; it spilled ~80 regs to buy nothing.
// Evidence chain: (1024,4)->64, (512,2)->128, (512,1)->128+spill.
// Fix: pin waves/EU to exactly 2 -> register budget 256, live set ~215.
// Hypothesis (unchanged, never validly tested): L1's W stream is 2MB/CU
// with 2x intra-WG duplication (~61 B/cyc/CU at floor ~ L2 ceiling 58);
// gs-split (wave = mrow x gs, kq halved, all 4 batches/wave) halves the
// stream and the per-wave wait events. Correctness of this exact structure
// harness-verified in R17 and R20 (absmax 0.5 pass both).
// Grid: 256 WGs x 512 thr = 1 WG/CU, 8 waves = 2/SIMD. LDS 112KB.

typedef __attribute__((ext_vector_type(8))) short short8;
typedef __attribute__((ext_vector_type(8))) __bf16 bf16x8;
typedef __attribute__((ext_vector_type(16))) float f32x16;
typedef __attribute__((ext_vector_type(4))) unsigned short u16x4;

#define DEVINL static __device__ __forceinline__

DEVINL unsigned short f2bf_rne(float f) {
  unsigned int u = __builtin_bit_cast(unsigned int, f);
  unsigned int r = u + 0x7fffu + ((u >> 16) & 1u);
  return (unsigned short)(r >> 16);
}

// async global->LDS, 16B per lane; LDS dest = wave-uniform base + lane*16
DEVINL void gload_lds16(const void* g, void* l) {
  __builtin_amdgcn_global_load_lds(
      (const __attribute__((address_space(1))) unsigned int*)g,
      (__attribute__((address_space(3))) unsigned int*)l, 16, 0, 0);
}

// MFMA adapter: builtin may want v8i16 or v8bf16. SFINAE both.
template <typename V>
DEVINL auto mfma_32x32x16_bf16(V a, V b, f32x16 c, int)
    -> decltype(__builtin_amdgcn_mfma_f32_32x32x16_bf16(a, b, c, 0, 0, 0)) {
  return __builtin_amdgcn_mfma_f32_32x32x16_bf16(a, b, c, 0, 0, 0);
}
template <typename V>
DEVINL f32x16 mfma_32x32x16_bf16(V a, V b, f32x16 c, long) {
  return __builtin_amdgcn_mfma_f32_32x32x16_bf16(
      __builtin_bit_cast(bf16x8, a), __builtin_bit_cast(bf16x8, b), c, 0, 0, 0);
}
DEVINL f32x16 mfma_bf16(short8 a, short8 b, f32x16 c) {
  return mfma_32x32x16_bf16(a, b, c, 0);
}

// ---------------- W pack kernel (unchanged, verified R2-R20) ----------------
// Packed layout per layer: [f][kb=k>>3][h][j=k&7] bf16 (granule = 1024 u16).
__global__ void pack_w_kernel(const float* __restrict__ W0,
                              const float* __restrict__ W1,
                              const float* __restrict__ W2,
                              unsigned short* __restrict__ Wt) {
  __shared__ float tile[8][132];
  const int u = blockIdx.x;
  const float* W; int FK, f, kb, base;
  if (u < 128)      { W = W0; FK = 32;  f = u >> 2;         kb = u & 3;          base = 0; }
  else if (u < 640) { W = W1; FK = 128; f = (u - 128) >> 4; kb = (u - 128) & 15; base = 131072; }
  else              { W = W2; FK = 128; f = (u - 640) >> 4; kb = (u - 640) & 15; base = 655360; }
  const int t = threadIdx.x;
#pragma unroll
  for (int i = 0; i < 4; ++i) {
    const int e = t + i * 256;  // 0..1023
    const int kk = e >> 7, h = e & 127;
    tile[kk][h] = W[(f * FK + kb * 8 + kk) * 128 + h];
  }
  __syncthreads();
  unsigned short* dst = Wt + base + f * (FK / 8) * 1024 + kb * 1024;
  const int h = t >> 1;
  const int j0 = (t & 1) * 4;
  u16x4 v;
  v.x = f2bf_rne(tile[j0 + 0][h]);
  v.y = f2bf_rne(tile[j0 + 1][h]);
  v.z = f2bf_rne(tile[j0 + 2][h]);
  v.w = f2bf_rne(tile[j0 + 3][h]);
  *(u16x4*)&dst[t * 4] = v;
}

// ------- layers 0/1: register W, wave = (mrow, gs), 4 n-tiles/wave ---------
// Frag (field f, global kq) at u16 offset f*FS + kq*2048 + half*1024 + hrow*8.
// Wave (mrow, gs): m-tile mrow, kq in [gs*KQG, gs*KQG+KQG), ALL 4 n-tiles
// (nt = batch). Partial Y sums over the gs pair reduced via `red` (64KB LDS);
// epilogue on gs==0 waves only. (Math harness-verified R17/R20.)
template <int KQG, int FS, int LAYER>
DEVINL void run_layer(const unsigned short* __restrict__ WtL,
                      const float* __restrict__ bias,
                      const float* x0l,  // LDS-resident x0 block [b][f][d]
                      float* __restrict__ outp, int outoff,
                      unsigned int* SB, float* red,
                      int lane, int mrow, int gs, int l31, int half) {
  __syncthreads();  // state in SB + x0l ready (prologue or previous epilogue)

  // B-frags (S) from SB into registers, once per layer.
  // slot (half,j) of sfr[nt][kq] holds S[r][k = (gs*KQG+kq)*16 + half*8 + j],
  // r = nt*32 + l31. SB row k2=k/2 packs (k even lo16, k odd hi16).
  int4 sfr[4][KQG];
#pragma unroll
  for (int nt = 0; nt < 4; ++nt) {
    const int r = nt * 32 + l31;
#pragma unroll
    for (int kq = 0; kq < KQG; ++kq) {
      const int row0 = (gs * KQG + kq) * 8 + half * 4;
      int4 v;
      v.x = (int)SB[(row0 + 0) * 128 + r];
      v.y = (int)SB[(row0 + 1) * 128 + r];
      v.z = (int)SB[(row0 + 2) * 128 + r];
      v.w = (int)SB[(row0 + 3) * 128 + r];
      sfr[nt][kq] = v;
    }
  }

  f32x16 zv;
#pragma unroll
  for (int e = 0; e < 16; ++e) zv[e] = 0.f;
  f32x16 outacc[4] = {zv, zv, zv, zv};

  const int hrow = mrow * 32 + l31;
  const unsigned short* gb =
      WtL + (size_t)(gs * KQG * 2048 + half * 1024 + hrow * 8);

  auto ldf = [&](short8* wv, int f) {  // this wave's KQG frags of field f
#pragma unroll
    for (int i = 0; i < KQG; ++i)
      wv[i] = *(const short8*)&gb[(size_t)f * FS + i * 2048];
  };
  auto doFld = [&](const short8* wv, int f) {
#pragma unroll
    for (int np = 0; np < 2; ++np) {  // n-tile pairs: keeps only 2 Y live
      const float xsA = x0l[(2 * np + 0) * 1024 + f * 32 + l31];
      const float xsB = x0l[(2 * np + 1) * 1024 + f * 32 + l31];
      f32x16 Y0, Y1;
#pragma unroll
      for (int i = 0; i < KQG; ++i) {
        const short8 sA = __builtin_bit_cast(short8, sfr[2 * np + 0][i]);
        const short8 sB = __builtin_bit_cast(short8, sfr[2 * np + 1][i]);
        Y0 = mfma_bf16(wv[i], sA, i == 0 ? zv : Y0);
        Y1 = mfma_bf16(wv[i], sB, i == 0 ? zv : Y1);
      }
#pragma unroll
      for (int e = 0; e < 16; ++e) {
        outacc[2 * np + 0][e] += xsA * Y0[e];
        outacc[2 * np + 1][e] += xsB * Y1[e];
      }
    }
  };

  short8 wa[KQG], wb[KQG];
  ldf(wa, 0);
  ldf(wb, 1);
#pragma unroll 1
  for (int f2 = 0; f2 < 16; ++f2) {
    const int f = 2 * f2;
    doFld(wa, f);
    if (f2 < 15) ldf(wa, f + 2);
    doFld(wb, f + 1);
    if (f2 < 15) ldf(wb, f + 3);
  }

  // --- gs partial-sum reduction (red: [mrow][nt][e][lane] f32, 64KB) ---
  if (gs) {
#pragma unroll
    for (int nt = 0; nt < 4; ++nt)
#pragma unroll
      for (int e = 0; e < 16; ++e)
        red[((mrow * 4 + nt) * 16 + e) * 64 + lane] = outacc[nt][e];
  }
  __syncthreads();  // partials visible; all sfr reads done -> SB writable
  if (gs) return;   // gs==1 waves rejoin at the next phase's entry barrier
#pragma unroll
  for (int nt = 0; nt < 4; ++nt)
#pragma unroll
    for (int e = 0; e < 16; ++e)
      outacc[nt][e] += red[((mrow * 4 + nt) * 16 + e) * 64 + lane];

  // --- epilogue (gs==0 waves; R12 math, nt = batch 0..3) ---
  // C/D layout: col = lane&31 = n; row = (reg&3)+8*(reg>>2)+4*half = h.
  float bv[16];
#pragma unroll
  for (int e = 0; e < 16; ++e)
    bv[e] = bias[mrow * 32 + (e & 3) + 8 * (e >> 2) + 4 * half];

  if constexpr (LAYER < 2) {
    // next state S'[r][h] = bf16(acc+bias), packed [h/2][r] u32 into SB
#pragma unroll
    for (int nt = 0; nt < 4; ++nt) {
      const int r = nt * 32 + l31;
#pragma unroll
      for (int g = 0; g < 4; ++g) {
        const int h2 = mrow * 16 + 4 * g + 2 * half;
        const float v0 = outacc[nt][4 * g + 0] + bv[4 * g + 0];
        const float v1 = outacc[nt][4 * g + 1] + bv[4 * g + 1];
        const float v2 = outacc[nt][4 * g + 2] + bv[4 * g + 2];
        const float v3 = outacc[nt][4 * g + 3] + bv[4 * g + 3];
        SB[h2 * 128 + r] =
            (unsigned)f2bf_rne(v0) | ((unsigned)f2bf_rne(v1) << 16);
        SB[(h2 + 1) * 128 + r] =
            (unsigned)f2bf_rne(v2) | ((unsigned)f2bf_rne(v3) << 16);
      }
    }
  }

  // final output: out[b, outoff+h] = sum_d acc + 32*bias (d = l31 lanes)
#pragma unroll
  for (int nt = 0; nt < 4; ++nt) {
    float sv[16];
#pragma unroll
    for (int e = 0; e < 16; ++e) {
      float v = outacc[nt][e];
      v += __shfl_xor(v, 1);
      v += __shfl_xor(v, 2);
      v += __shfl_xor(v, 4);
      v += __shfl_xor(v, 8);
      v += __shfl_xor(v, 16);
      sv[e] = v + 32.0f * bv[e];
    }
    if (l31 == 0) {
      const int b = nt;
#pragma unroll
      for (int g = 0; g < 4; ++g) {
        const int h = mrow * 32 + 8 * g + 4 * half;
        float4 o = {sv[4 * g + 0], sv[4 * g + 1], sv[4 * g + 2], sv[4 * g + 3]};
        *(float4*)&outp[b * 384 + outoff + h] = o;
      }
    }
  }
}

// ---------------- layer 2, U-trick (R19's 4-deep step2, measured) ----------
// out2[b,h] = sum_k U[b,k]*W2[k,h] + 32*b2[h];  U[b,f*128+g] = x0_b . S2_b^T.
DEVINL void run_layer2_fast(const unsigned short* __restrict__ WtL,
                            const float* __restrict__ bias,
                            const float* x0l,
                            float* __restrict__ outp,
                            unsigned int* SB,
                            int w, int l31, int half, int tid) {
  __syncthreads();  // S2 in SB ready ([g/2][r=b*32+d] u32 bf16-pairs)

  f32x16 zv;
#pragma unroll
  for (int e = 0; e < 16; ++e) zv[e] = 0.f;

  // ---- step 1: U = x0_b (32f x 32d) . S2_b^T (32d x 128g), MFMA M=f,N=g,K=d
  // wave w: batch bw = w>>1, g-half gh = w&1 (2 n-tiles of g).
  const int bw = w >> 1, gh = w & 1;
  short8 a1[2];  // A[m=f=l31][k=d slots], kq=0,1  (reads from LDS x0l)
  {
    const float* xr = &x0l[bw * 1024 + l31 * 32];
#pragma unroll
    for (int kq = 0; kq < 2; ++kq) {
      const int d0 = kq * 16 + half * 8;
      union { short8 v; unsigned short u[8]; } t;
#pragma unroll
      for (int j = 0; j < 8; ++j) t.u[j] = f2bf_rne(xr[d0 + j]);
      a1[kq] = t.v;
    }
  }
  short8 bfr[2][2];  // [nt][kq]: B[k=d][n=g]: S2[b, g, d]
#pragma unroll
  for (int nt = 0; nt < 2; ++nt) {
    const int g = gh * 64 + nt * 32 + l31;
    const unsigned int* row = &SB[(g >> 1) * 128 + bw * 32];
    const int sh = (g & 1) * 16;
#pragma unroll
    for (int kq = 0; kq < 2; ++kq) {
      const int d0 = kq * 16 + half * 8;
      union { short8 v; unsigned short u[8]; } t;
#pragma unroll
      for (int j = 0; j < 8; ++j)
        t.u[j] = (unsigned short)(row[d0 + j] >> sh);
      bfr[nt][kq] = t.v;
    }
  }
  f32x16 ua[2];
#pragma unroll
  for (int nt = 0; nt < 2; ++nt) {
    ua[nt] = mfma_bf16(a1[0], bfr[nt][0], zv);
    ua[nt] = mfma_bf16(a1[1], bfr[nt][1], ua[nt]);
  }
  __syncthreads();  // all waves done reading S2 from SB

  // ---- write U into SB as U32[k2 = k/2][b] (k = f*128+g; u16 writes) ----
  unsigned short* U16 = (unsigned short*)SB;
#pragma unroll
  for (int nt = 0; nt < 2; ++nt) {
    const int g = gh * 64 + nt * 32 + l31;
#pragma unroll
    for (int reg = 0; reg < 16; ++reg) {
      const int f = (reg & 3) + 8 * (reg >> 2) + 4 * half;
      const int k = f * 128 + g;
      U16[(k >> 1) * 8 + bw * 2 + (k & 1)] = f2bf_rne(ua[nt][reg]);
    }
  }
  __syncthreads();  // U ready

  // ---- step 2: D[m=h][n=b] = sum_k W2[k,h]*U[b,k]; wave: mt=w&3, kh=w>>2 ----
  const int mt = w & 3, kh = w >> 2;
  const char* gb = (const char*)WtL +
                   (size_t)(half * 2048 + (mt * 32 + l31) * 16);
  const int bl = l31 & 3;  // lanes 4..31 duplicate b (cols unused, bounds-safe)

  auto ldq2 = [&](short8* wv, int q) {  // quad q -> kq = 4q..4q+3
#pragma unroll
    for (int i = 0; i < 4; ++i)
      wv[i] = *(const short8*)(gb + (size_t)q * 16384 + i * 4096);
  };
  auto breadq = [&](short8* bv, int q) {  // B-frags for the 4 kq of quad q
#pragma unroll
    for (int i = 0; i < 4; ++i) {
      const int row0 = (q * 4 + i) * 8 + half * 4;
      int4 v;
      v.x = (int)SB[(row0 + 0) * 4 + bl];
      v.y = (int)SB[(row0 + 1) * 4 + bl];
      v.z = (int)SB[(row0 + 2) * 4 + bl];
      v.w = (int)SB[(row0 + 3) * 4 + bl];
      bv[i] = __builtin_bit_cast(short8, v);
    }
  };

  f32x16 acc0 = zv, acc1 = zv;
  short8 qa[4], qb[4], qc[4], qd[4], Ba[4], Bb[4], Bc[4], Bd[4];
  const int q0 = kh * 32;  // 32 quads = 128 kq per wave
  ldq2(qa, q0 + 0); breadq(Ba, q0 + 0);
  ldq2(qb, q0 + 1); breadq(Bb, q0 + 1);
  ldq2(qc, q0 + 2); breadq(Bc, q0 + 2);
  ldq2(qd, q0 + 3); breadq(Bd, q0 + 3);
#pragma unroll 1
  for (int qq = 0; qq < 8; ++qq) {  // 4 quads per iteration
    const int q = q0 + 4 * qq;
    const bool more = qq < 7;
#pragma unroll
    for (int i = 0; i < 4; ++i) acc0 = mfma_bf16(qa[i], Ba[i], acc0);
    { const int r = more ? q + 4 : q0; ldq2(qa, r); breadq(Ba, r); }
#pragma unroll
    for (int i = 0; i < 4; ++i) acc1 = mfma_bf16(qb[i], Bb[i], acc1);
    { const int r = more ? q + 5 : q0; ldq2(qb, r); breadq(Bb, r); }
#pragma unroll
    for (int i = 0; i < 4; ++i) acc0 = mfma_bf16(qc[i], Bc[i], acc0);
    { const int r = more ? q + 6 : q0; ldq2(qc, r); breadq(Bc, r); }
#pragma unroll
    for (int i = 0; i < 4; ++i) acc1 = mfma_bf16(qd[i], Bd[i], acc1);
    { const int r = more ? q + 7 : q0; ldq2(qd, r); breadq(Bd, r); }
  }
#pragma unroll
  for (int e = 0; e < 16; ++e) acc0[e] += acc1[e];

  __syncthreads();  // all waves done reading U from SB

  // ---- partials P[o = b*128 + h][kh] f32 into SB (4KB), then reduce ----
  float* P = (float*)SB;
  if (l31 < 4) {
#pragma unroll
    for (int reg = 0; reg < 16; ++reg) {
      const int h = mt * 32 + (reg & 3) + 8 * (reg >> 2) + 4 * half;
      P[(l31 * 128 + h) * 2 + kh] = acc0[reg];
    }
  }
  __syncthreads();
  {
    const int b = tid >> 7, h = tid & 127;  // tid 0..511 -> all outputs
    const float v = P[tid * 2] + P[tid * 2 + 1] + 32.0f * bias[h];
    outp[b * 384 + 256 + h] = v;
  }
}

__global__ __launch_bounds__(512, 1)
__attribute__((amdgpu_waves_per_eu(2, 2))) void cin_kernel(
    const float* __restrict__ x0g, const unsigned short* __restrict__ Wt,
    const float* __restrict__ b0, const float* __restrict__ b1,
    const float* __restrict__ b2, float* __restrict__ out) {
  __shared__ unsigned int SB[64 * 128];       // 32KB state / U / partials
  __shared__ __align__(16) float x0l[4096];   // 16KB x0 block [b][f][d]
  __shared__ __align__(16) float red[16384];  // 64KB gs-reduction scratch

  const int t = threadIdx.x;
  const int lane = t & 63;
  const int w = t >> 6;    // 0..7
  const int mrow = w & 3;  // h-tile of 32 (L0/L1)
  const int gs = w >> 2;   // kq-half split (L0/L1)
  const int l31 = lane & 31, half = lane >> 5;
  const int wgb0 = blockIdx.x * 4;  // 4 batches per WG

  // prologue A: stage x0 block -> LDS via global_load_lds (16 chunks x 1KB)
  const float* xsrc = x0g + (size_t)wgb0 * 1024;
#pragma unroll
  for (int c = 0; c < 2; ++c) {
    const int chunk = w * 2 + c;
    gload_lds16(xsrc + chunk * 256 + lane * 4, x0l + chunk * 256);
  }
  // prologue B: S1 = bf16(x0^T) -> SB ([g/2][r] u32, r = b_local*32+d)
#pragma unroll
  for (int s = 0; s < 4; ++s) {
    const int i = t + s * 512;  // 0..2047
    const int r = i & 127, g2 = i >> 7;
    const float* p = &x0g[(wgb0 + (r >> 5)) * 1024 + (2 * g2) * 32 + (r & 31)];
    SB[g2 * 128 + r] =
        (unsigned)f2bf_rne(p[0]) | ((unsigned)f2bf_rne(p[32]) << 16);
  }
  // visibility handled by the entry barrier in run_layer (full drain)

  float* outp = out + (size_t)wgb0 * 384;
  run_layer<1, 4096, 0>(Wt, b0, x0l, outp, 0, SB, red, lane, mrow, gs, l31,
                        half);
  run_layer<4, 16384, 1>(Wt + 131072, b1, x0l, outp, 128, SB, red, lane, mrow,
                         gs, l31, half);
  run_layer2_fast(Wt + 655360, b2, x0l, outp, SB, w, l31, half, t);
}

extern "C" void kernel_launch(void* const* d_in, const int* in_sizes, int n_in,
                              void* d_out, int out_size, void* d_ws, size_t ws_size,
                              hipStream_t stream) {
  (void)in_sizes; (void)n_in; (void)out_size; (void)ws_size;
  const float* x0 = (const float*)d_in[0];
  const float* W0 = (const float*)d_in[1];
  const float* W1 = (const float*)d_in[2];
  const float* W2 = (const float*)d_in[3];
  const float* b0 = (const float*)d_in[4];
  const float* b1 = (const float*)d_in[5];
  const float* b2 = (const float*)d_in[6];
  unsigned short* Wt = (unsigned short*)d_ws;  // 2,359,296 B

  pack_w_kernel<<<1152, 256, 0, stream>>>(W0, W1, W2, Wt);
  // 256 WGs x 512 thr = 1 WG/CU (8 waves, 2/SIMD)
  cin_kernel<<<256, 512, 0, stream>>>(x0, Wt, b0, b1, b2, (float*)d_out);
}

// Round 10
// 131.914 us; speedup vs baseline: 1.5076x; 1.5076x over previous
//
#include <hip/hip_runtime.h>
#include <hip/hip_bf16.h>

// CIN (xDeepFM) fused 3-layer kernel for MI355X — R22: R19 (best verified,
// 65.5us) + per-block ROTATED W walk order to kill coincident-burst L2
// congestion.
// R20/R21 post-mortem: allocator hard-caps at 128 VGPR (waves_per_eu
// ignored); W-dedup axis closed for good. R19 model: MFMA floor 20.5us
// (== MfmaUtil 34% x 65.5), L1 L2-demand ~ per-XCD ceiling, yet we're
// latency-crushed not streaming: all 256 WGs walk IDENTICAL W addresses in
// lockstep -> every field step ~2048 waves hit the same 32KB burst ->
// L2 queueing delay >> unloaded 200-500cyc, and 2 waves/SIMD can't hide it.
// Fix: each block walks fields/quads as a ring starting at rotation
// ((cu*5 + xcd) & 31) (coprime stride -> uniform spread per XCD); npair
// waves (duplicate addresses) offset by half a ring. Accumulation is
// order-independent; ring wrap replaces the last-iter clamp (in-bounds).
// L1/L0/step2 rotated; everything else byte-identical to R19.
// Grid: 256 WGs x 512 thr = 1 WG/CU, 8 waves = 2/SIMD. LDS 48KB.

typedef __attribute__((ext_vector_type(8))) short short8;
typedef __attribute__((ext_vector_type(8))) __bf16 bf16x8;
typedef __attribute__((ext_vector_type(16))) float f32x16;
typedef __attribute__((ext_vector_type(4))) unsigned short u16x4;

#define DEVINL static __device__ __forceinline__

DEVINL unsigned short f2bf_rne(float f) {
  unsigned int u = __builtin_bit_cast(unsigned int, f);
  unsigned int r = u + 0x7fffu + ((u >> 16) & 1u);
  return (unsigned short)(r >> 16);
}

// async global->LDS, 16B per lane; LDS dest = wave-uniform base + lane*16
DEVINL void gload_lds16(const void* g, void* l) {
  __builtin_amdgcn_global_load_lds(
      (const __attribute__((address_space(1))) unsigned int*)g,
      (__attribute__((address_space(3))) unsigned int*)l, 16, 0, 0);
}

// MFMA adapter: builtin may want v8i16 or v8bf16. SFINAE both.
template <typename V>
DEVINL auto mfma_32x32x16_bf16(V a, V b, f32x16 c, int)
    -> decltype(__builtin_amdgcn_mfma_f32_32x32x16_bf16(a, b, c, 0, 0, 0)) {
  return __builtin_amdgcn_mfma_f32_32x32x16_bf16(a, b, c, 0, 0, 0);
}
template <typename V>
DEVINL f32x16 mfma_32x32x16_bf16(V a, V b, f32x16 c, long) {
  return __builtin_amdgcn_mfma_f32_32x32x16_bf16(
      __builtin_bit_cast(bf16x8, a), __builtin_bit_cast(bf16x8, b), c, 0, 0, 0);
}
DEVINL f32x16 mfma_bf16(short8 a, short8 b, f32x16 c) {
  return mfma_32x32x16_bf16(a, b, c, 0);
}

// ---------------- W pack kernel (unchanged, verified R2-R21) ----------------
// Packed layout per layer: [f][kb=k>>3][h][j=k&7] bf16 (granule = 1024 u16).
__global__ void pack_w_kernel(const float* __restrict__ W0,
                              const float* __restrict__ W1,
                              const float* __restrict__ W2,
                              unsigned short* __restrict__ Wt) {
  __shared__ float tile[8][132];
  const int u = blockIdx.x;
  const float* W; int FK, f, kb, base;
  if (u < 128)      { W = W0; FK = 32;  f = u >> 2;         kb = u & 3;          base = 0; }
  else if (u < 640) { W = W1; FK = 128; f = (u - 128) >> 4; kb = (u - 128) & 15; base = 131072; }
  else              { W = W2; FK = 128; f = (u - 640) >> 4; kb = (u - 640) & 15; base = 655360; }
  const int t = threadIdx.x;
#pragma unroll
  for (int i = 0; i < 4; ++i) {
    const int e = t + i * 256;  // 0..1023
    const int kk = e >> 7, h = e & 127;
    tile[kk][h] = W[(f * FK + kb * 8 + kk) * 128 + h];
  }
  __syncthreads();
  unsigned short* dst = Wt + base + f * (FK / 8) * 1024 + kb * 1024;
  const int h = t >> 1;
  const int j0 = (t & 1) * 4;
  u16x4 v;
  v.x = f2bf_rne(tile[j0 + 0][h]);
  v.y = f2bf_rne(tile[j0 + 1][h]);
  v.z = f2bf_rne(tile[j0 + 2][h]);
  v.w = f2bf_rne(tile[j0 + 3][h]);
  *(u16x4*)&dst[t * 4] = v;
}

// ------- layers 0/1 (R19 structure + rotated field/quad ring walk) ---------
// Quad = 4 granule loads (16B/lane). Field f (KQ=8) = quads (2f, 2f+1).
// Per-lane granule addr: gb + q*16384 + i*4096 bytes (i = 0..3).
// Ring: step s visits field (s+R)&31 (L1) / quad (s+R0)&15 (L0); reload
// targets step s+2 — wrap past the end reloads visited (unused) entries.
template <int KQ, int STEPS, int LAYER>
DEVINL void run_layer(const unsigned short* __restrict__ WtL,
                      const float* __restrict__ bias,
                      const float* x0l,  // LDS-resident x0 block [b][f][d]
                      float* __restrict__ outp, int outoff,
                      unsigned int* SB,
                      int wgb0, int mrow, int npair, int l31, int half) {
  __syncthreads();  // state in SB + x0l ready (prologue or previous epilogue)

  // B-frags (S) from SB into registers, once per layer.
  int4 sfr[2][KQ];
  const int rb = npair * 64;
#pragma unroll
  for (int nt = 0; nt < 2; ++nt) {
    const int r = rb + nt * 32 + l31;
#pragma unroll
    for (int kq = 0; kq < KQ; ++kq) {
      const int row0 = kq * 8 + half * 4;
      int4 v;
      v.x = (int)SB[(row0 + 0) * 128 + r];
      v.y = (int)SB[(row0 + 1) * 128 + r];
      v.z = (int)SB[(row0 + 2) * 128 + r];
      v.w = (int)SB[(row0 + 3) * 128 + r];
      sfr[nt][kq] = v;
    }
  }

  f32x16 zv;
#pragma unroll
  for (int e = 0; e < 16; ++e) zv[e] = 0.f;
  f32x16 outacc[2] = {zv, zv};

  const char* gb = (const char*)WtL +
                   (size_t)(half * 2048 + (mrow * 32 + l31) * 16);
  const int xb0 = (npair * 2 + 0) * 1024 + l31;  // x0l[b_local][f][d=l31]
  const int xb1 = (npair * 2 + 1) * 1024 + l31;

  const int bid = wgb0 >> 2;
  const int rbase = (bid >> 3) * 5 + (bid & 7);  // spread within each XCD

  auto ldg1 = [&](int q, int i) -> short8 {  // granule i of quad q
    return *(const short8*)(gb + (size_t)q * 16384 + (size_t)i * 4096);
  };
  auto ldq = [&](short8* wv, int q) {
#pragma unroll
    for (int i = 0; i < 4; ++i) wv[i] = ldg1(q, i);
  };

  if constexpr (KQ == 8) {
    // L1: field ring of 32, per-block rotation + npair half-ring offset.
    const int R = (rbase + npair * 16) & 31;
    auto fldOf = [&](int s) { return (s + R) & 31; };

    short8 w0[4], w1[4], w2[4], w3[4];
    ldq(w0, 2 * fldOf(0));
    ldq(w1, 2 * fldOf(0) + 1);
    ldq(w2, 2 * fldOf(1));
    ldq(w3, 2 * fldOf(1) + 1);
    __syncthreads();  // all waves hold sfr; SB free for this layer's epilogue

    auto doFldR = [&](short8* qa, short8* qb, float xs0, float xs1, int fnext) {
      f32x16 Y0, Y1;
#pragma unroll
      for (int i = 0; i < 4; ++i) {
        const short8 s0 = __builtin_bit_cast(short8, sfr[0][i]);
        const short8 s1 = __builtin_bit_cast(short8, sfr[1][i]);
        Y0 = mfma_bf16(qa[i], s0, i == 0 ? zv : Y0);
        Y1 = mfma_bf16(qa[i], s1, i == 0 ? zv : Y1);
      }
#pragma unroll
      for (int i = 0; i < 4; ++i) qa[i] = ldg1(2 * fnext, i);  // reload s+2
#pragma unroll
      for (int i = 0; i < 4; ++i) {
        const short8 s0 = __builtin_bit_cast(short8, sfr[0][4 + i]);
        const short8 s1 = __builtin_bit_cast(short8, sfr[1][4 + i]);
        Y0 = mfma_bf16(qb[i], s0, Y0);
        Y1 = mfma_bf16(qb[i], s1, Y1);
      }
#pragma unroll
      for (int i = 0; i < 4; ++i) qb[i] = ldg1(2 * fnext + 1, i);
#pragma unroll
      for (int e = 0; e < 16; ++e) {
        outacc[0][e] += xs0 * Y0[e];
        outacc[1][e] += xs1 * Y1[e];
      }
    };

#pragma unroll 1
    for (int it = 0; it < 16; ++it) {
      const int s0 = 2 * it, s1 = 2 * it + 1;
      const int f0 = fldOf(s0), f1 = fldOf(s1);
      const float xs00 = x0l[xb0 + f0 * 32], xs01 = x0l[xb1 + f0 * 32];
      const float xs10 = x0l[xb0 + f1 * 32], xs11 = x0l[xb1 + f1 * 32];
      doFldR(w0, w1, xs00, xs01, fldOf(s0 + 2));  // wrap = visited, unused
      doFldR(w2, w3, xs10, xs11, fldOf(s1 + 2));
    }
  } else {
    // L0 (KQ=2): quad ring of 16 (quad q = fields 2q, 2q+1).
    const int R0 = ((bid >> 3) * 3 + (bid & 7) + npair * 8) & 15;
    auto qOf = [&](int s) { return (s + R0) & 15; };

    short8 wa[4], wb[4];
    ldq(wa, qOf(0));
    ldq(wb, qOf(1));
    __syncthreads();

    const short8 s00 = __builtin_bit_cast(short8, sfr[0][0]);
    const short8 s01 = __builtin_bit_cast(short8, sfr[0][1]);
    const short8 s10 = __builtin_bit_cast(short8, sfr[1][0]);
    const short8 s11 = __builtin_bit_cast(short8, sfr[1][1]);

    auto doQR = [&](short8* wv, float x0a, float x1a, float x0b, float x1b,
                    int qrel) {
      f32x16 Y0 = mfma_bf16(wv[0], s00, zv);
      f32x16 Y1 = mfma_bf16(wv[0], s10, zv);
      Y0 = mfma_bf16(wv[1], s01, Y0);
      Y1 = mfma_bf16(wv[1], s11, Y1);
      wv[0] = ldg1(qrel, 0);  // reload for ring step s+2
      wv[1] = ldg1(qrel, 1);
#pragma unroll
      for (int e = 0; e < 16; ++e) {
        outacc[0][e] += x0a * Y0[e];
        outacc[1][e] += x1a * Y1[e];
      }
      f32x16 Z0 = mfma_bf16(wv[2], s00, zv);
      f32x16 Z1 = mfma_bf16(wv[2], s10, zv);
      Z0 = mfma_bf16(wv[3], s01, Z0);
      Z1 = mfma_bf16(wv[3], s11, Z1);
      wv[2] = ldg1(qrel, 2);
      wv[3] = ldg1(qrel, 3);
#pragma unroll
      for (int e = 0; e < 16; ++e) {
        outacc[0][e] += x0b * Z0[e];
        outacc[1][e] += x1b * Z1[e];
      }
    };

#pragma unroll 1
    for (int q2 = 0; q2 < 8; ++q2) {
      const int sa = 2 * q2, sb = 2 * q2 + 1;
      const int qa_ = qOf(sa), qb_ = qOf(sb);
      const float xA0 = x0l[xb0 + (2 * qa_ + 0) * 32];
      const float xA1 = x0l[xb1 + (2 * qa_ + 0) * 32];
      const float xB0 = x0l[xb0 + (2 * qa_ + 1) * 32];
      const float xB1 = x0l[xb1 + (2 * qa_ + 1) * 32];
      const float xC0 = x0l[xb0 + (2 * qb_ + 0) * 32];
      const float xC1 = x0l[xb1 + (2 * qb_ + 0) * 32];
      const float xD0 = x0l[xb0 + (2 * qb_ + 1) * 32];
      const float xD1 = x0l[xb1 + (2 * qb_ + 1) * 32];
      doQR(wa, xA0, xA1, xB0, xB1, qOf(sa + 2));
      doQR(wb, xC0, xC1, xD0, xD1, qOf(sb + 2));
    }
  }

  // --- epilogue (verbatim R12/R19) ---
  // C/D layout: col = lane&31 = n; row = (reg&3)+8*(reg>>2)+4*half = h.
  float bv[16];
#pragma unroll
  for (int e = 0; e < 16; ++e)
    bv[e] = bias[mrow * 32 + (e & 3) + 8 * (e >> 2) + 4 * half];

  if constexpr (LAYER < 2) {
    // next state S'[r][h] = bf16(acc+bias), packed [h/2][r] u32 into SB
#pragma unroll
    for (int nt = 0; nt < 2; ++nt) {
      const int r = rb + nt * 32 + l31;
#pragma unroll
      for (int g = 0; g < 4; ++g) {
        const int h2 = mrow * 16 + 4 * g + 2 * half;
        const float v0 = outacc[nt][4 * g + 0] + bv[4 * g + 0];
        const float v1 = outacc[nt][4 * g + 1] + bv[4 * g + 1];
        const float v2 = outacc[nt][4 * g + 2] + bv[4 * g + 2];
        const float v3 = outacc[nt][4 * g + 3] + bv[4 * g + 3];
        SB[h2 * 128 + r] =
            (unsigned)f2bf_rne(v0) | ((unsigned)f2bf_rne(v1) << 16);
        SB[(h2 + 1) * 128 + r] =
            (unsigned)f2bf_rne(v2) | ((unsigned)f2bf_rne(v3) << 16);
      }
    }
  }

  // final output: out[b, outoff+h] = sum_d acc + 32*bias (d = l31 lanes)
#pragma unroll
  for (int nt = 0; nt < 2; ++nt) {
    float sv[16];
#pragma unroll
    for (int e = 0; e < 16; ++e) {
      float v = outacc[nt][e];
      v += __shfl_xor(v, 1);
      v += __shfl_xor(v, 2);
      v += __shfl_xor(v, 4);
      v += __shfl_xor(v, 8);
      v += __shfl_xor(v, 16);
      sv[e] = v + 32.0f * bv[e];
    }
    if (l31 == 0) {
      const int b = npair * 2 + nt;
#pragma unroll
      for (int g = 0; g < 4; ++g) {
        const int h = mrow * 32 + 8 * g + 4 * half;
        float4 o = {sv[4 * g + 0], sv[4 * g + 1], sv[4 * g + 2], sv[4 * g + 3]};
        *(float4*)&outp[b * 384 + outoff + h] = o;
      }
    }
  }
}

// -------- layer 2, U-trick (R19 4-deep step2 + rotated quad ring) ----------
// out2[b,h] = sum_k U[b,k]*W2[k,h] + 32*b2[h];  U[b,f*128+g] = x0_b . S2_b^T.
DEVINL void run_layer2_fast(const unsigned short* __restrict__ WtL,
                            const float* __restrict__ bias,
                            const float* x0l,
                            float* __restrict__ outp,
                            unsigned int* SB, int wgb0,
                            int w, int l31, int half, int tid) {
  __syncthreads();  // S2 in SB ready ([g/2][r=b*32+d] u32 bf16-pairs)

  f32x16 zv;
#pragma unroll
  for (int e = 0; e < 16; ++e) zv[e] = 0.f;

  // ---- step 1: U = x0_b (32f x 32d) . S2_b^T (32d x 128g), MFMA M=f,N=g,K=d
  const int bw = w >> 1, gh = w & 1;
  short8 a1[2];  // A[m=f=l31][k=d slots], kq=0,1  (reads from LDS x0l)
  {
    const float* xr = &x0l[bw * 1024 + l31 * 32];
#pragma unroll
    for (int kq = 0; kq < 2; ++kq) {
      const int d0 = kq * 16 + half * 8;
      union { short8 v; unsigned short u[8]; } t;
#pragma unroll
      for (int j = 0; j < 8; ++j) t.u[j] = f2bf_rne(xr[d0 + j]);
      a1[kq] = t.v;
    }
  }
  short8 bfr[2][2];  // [nt][kq]: B[k=d][n=g]: S2[b, g, d]
#pragma unroll
  for (int nt = 0; nt < 2; ++nt) {
    const int g = gh * 64 + nt * 32 + l31;
    const unsigned int* row = &SB[(g >> 1) * 128 + bw * 32];
    const int sh = (g & 1) * 16;
#pragma unroll
    for (int kq = 0; kq < 2; ++kq) {
      const int d0 = kq * 16 + half * 8;
      union { short8 v; unsigned short u[8]; } t;
#pragma unroll
      for (int j = 0; j < 8; ++j)
        t.u[j] = (unsigned short)(row[d0 + j] >> sh);
      bfr[nt][kq] = t.v;
    }
  }
  f32x16 ua[2];
#pragma unroll
  for (int nt = 0; nt < 2; ++nt) {
    ua[nt] = mfma_bf16(a1[0], bfr[nt][0], zv);
    ua[nt] = mfma_bf16(a1[1], bfr[nt][1], ua[nt]);
  }
  __syncthreads();  // all waves done reading S2 from SB

  // ---- write U into SB as U32[k2 = k/2][b] (k = f*128+g; u16 writes) ----
  unsigned short* U16 = (unsigned short*)SB;
#pragma unroll
  for (int nt = 0; nt < 2; ++nt) {
    const int g = gh * 64 + nt * 32 + l31;
#pragma unroll
    for (int reg = 0; reg < 16; ++reg) {
      const int f = (reg & 3) + 8 * (reg >> 2) + 4 * half;
      const int k = f * 128 + g;
      U16[(k >> 1) * 8 + bw * 2 + (k & 1)] = f2bf_rne(ua[nt][reg]);
    }
  }
  __syncthreads();  // U ready

  // ---- step 2: D[m=h][n=b] = sum_k W2[k,h]*U[b,k]; wave: mt=w&3, kh=w>>2 ----
  const int mt = w & 3, kh = w >> 2;
  const char* gb = (const char*)WtL +
                   (size_t)(half * 2048 + (mt * 32 + l31) * 16);
  const int bl = l31 & 3;  // lanes 4..31 duplicate b (cols unused, bounds-safe)

  const int bid = wgb0 >> 2;
  const int R2 = ((bid >> 3) * 5 + (bid & 7)) & 31;

  auto ldq2 = [&](short8* wv, int q) {  // quad q -> kq = 4q..4q+3
#pragma unroll
    for (int i = 0; i < 4; ++i)
      wv[i] = *(const short8*)(gb + (size_t)q * 16384 + i * 4096);
  };
  auto breadq = [&](short8* bv, int q) {  // B-frags for the 4 kq of quad q
#pragma unroll
    for (int i = 0; i < 4; ++i) {
      const int row0 = (q * 4 + i) * 8 + half * 4;
      int4 v;
      v.x = (int)SB[(row0 + 0) * 4 + bl];
      v.y = (int)SB[(row0 + 1) * 4 + bl];
      v.z = (int)SB[(row0 + 2) * 4 + bl];
      v.w = (int)SB[(row0 + 3) * 4 + bl];
      bv[i] = __builtin_bit_cast(short8, v);
    }
  };

  f32x16 acc0 = zv, acc1 = zv;
  short8 qa[4], qb[4], qc[4], qd[4], Ba[4], Bb[4], Bc[4], Bd[4];
  const int q0 = kh * 32;  // 32 quads = 128 kq per wave, ring-rotated
  auto qj = [&](int j) { return q0 + ((j + R2) & 31); };
  ldq2(qa, qj(0)); breadq(Ba, qj(0));
  ldq2(qb, qj(1)); breadq(Bb, qj(1));
  ldq2(qc, qj(2)); breadq(Bc, qj(2));
  ldq2(qd, qj(3)); breadq(Bd, qj(3));
#pragma unroll 1
  for (int qq = 0; qq < 8; ++qq) {  // 4 quads per iteration
    const int j = 4 * qq;
#pragma unroll
    for (int i = 0; i < 4; ++i) acc0 = mfma_bf16(qa[i], Ba[i], acc0);
    { const int r = qj(j + 4); ldq2(qa, r); breadq(Ba, r); }  // wrap = unused
#pragma unroll
    for (int i = 0; i < 4; ++i) acc1 = mfma_bf16(qb[i], Bb[i], acc1);
    { const int r = qj(j + 5); ldq2(qb, r); breadq(Bb, r); }
#pragma unroll
    for (int i = 0; i < 4; ++i) acc0 = mfma_bf16(qc[i], Bc[i], acc0);
    { const int r = qj(j + 6); ldq2(qc, r); breadq(Bc, r); }
#pragma unroll
    for (int i = 0; i < 4; ++i) acc1 = mfma_bf16(qd[i], Bd[i], acc1);
    { const int r = qj(j + 7); ldq2(qd, r); breadq(Bd, r); }
  }
#pragma unroll
  for (int e = 0; e < 16; ++e) acc0[e] += acc1[e];

  __syncthreads();  // all waves done reading U from SB

  // ---- partials P[o = b*128 + h][kh] f32 into SB (4KB), then reduce ----
  float* P = (float*)SB;
  if (l31 < 4) {
#pragma unroll
    for (int reg = 0; reg < 16; ++reg) {
      const int h = mt * 32 + (reg & 3) + 8 * (reg >> 2) + 4 * half;
      P[(l31 * 128 + h) * 2 + kh] = acc0[reg];
    }
  }
  __syncthreads();
  {
    const int b = tid >> 7, h = tid & 127;  // tid 0..511 -> all outputs
    const float v = P[tid * 2] + P[tid * 2 + 1] + 32.0f * bias[h];
    outp[b * 384 + 256 + h] = v;
  }
}

__global__ __launch_bounds__(512, 1) void cin_kernel(
    const float* __restrict__ x0g, const unsigned short* __restrict__ Wt,
    const float* __restrict__ b0, const float* __restrict__ b1,
    const float* __restrict__ b2, float* __restrict__ out) {
  __shared__ unsigned int SB[64 * 128];  // 32KB state / U / partials
  __shared__ __align__(16) float x0l[4096];  // 16KB x0 block [b][f][d]

  const int t = threadIdx.x;
  const int lane = t & 63;
  const int w = t >> 6;      // 0..7
  const int mrow = w & 3;    // h-tile of 32 (L0/L1)
  const int npair = w >> 2;  // batch pair (L0/L1)
  const int l31 = lane & 31, half = lane >> 5;
  const int wgb0 = blockIdx.x * 4;  // 4 batches per WG

  // prologue A: stage x0 block -> LDS via global_load_lds (16 chunks x 1KB)
  const float* xsrc = x0g + (size_t)wgb0 * 1024;
#pragma unroll
  for (int c = 0; c < 2; ++c) {
    const int chunk = w * 2 + c;
    gload_lds16(xsrc + chunk * 256 + lane * 4, x0l + chunk * 256);
  }
  // prologue B: S1 = bf16(x0^T) -> SB ([g/2][r] u32, r = b_local*32+d)
#pragma unroll
  for (int s = 0; s < 4; ++s) {
    const int i = t + s * 512;  // 0..2047
    const int r = i & 127, g2 = i >> 7;
    const float* p = &x0g[(wgb0 + (r >> 5)) * 1024 + (2 * g2) * 32 + (r & 31)];
    SB[g2 * 128 + r] =
        (unsigned)f2bf_rne(p[0]) | ((unsigned)f2bf_rne(p[32]) << 16);
  }
  // visibility handled by the entry barrier in run_layer (full drain)

  float* outp = out + (size_t)wgb0 * 384;
  run_layer<2, 8, 0>(Wt, b0, x0l, outp, 0, SB, wgb0, mrow, npair, l31, half);
  run_layer<8, 32, 1>(Wt + 131072, b1, x0l, outp, 128, SB,
                      wgb0, mrow, npair, l31, half);
  run_layer2_fast(Wt + 655360, b2, x0l, outp, SB, wgb0, w, l31, half, t);
}

extern "C" void kernel_launch(void* const* d_in, const int* in_sizes, int n_in,
                              void* d_out, int out_size, void* d_ws, size_t ws_size,
                              hipStream_t stream) {
  (void)in_sizes; (void)n_in; (void)out_size; (void)ws_size;
  const float* x0 = (const float*)d_in[0];
  const float* W0 = (const float*)d_in[1];
  const float* W1 = (const float*)d_in[2];
  const float* W2 = (const float*)d_in[3];
  const float* b0 = (const float*)d_in[4];
  const float* b1 = (const float*)d_in[5];
  const float* b2 = (const float*)d_in[6];
  unsigned short* Wt = (unsigned short*)d_ws;  // 2,359,296 B

  pack_w_kernel<<<1152, 256, 0, stream>>>(W0, W1, W2, Wt);
  // 256 WGs x 512 thr = 1 WG/CU (8 waves, 2/SIMD)
  cin_kernel<<<256, 512, 0, stream>>>(x0, Wt, b0, b1, b2, (float*)d_out);
}